// Round 10
// baseline (897.459 us; speedup 1.0000x reference)
//
#include <hip/hip_runtime.h>
#include <math.h>

// PhaseNN on MI355X.  ROUND 10: native trig + hoisted prefetch (R9 structure kept).
// R9 counters: per-eval 22.3k cyc = MFMA 5k + VALU 11k (== 32 precise __sincosf/lane!)
// + ~6k load latency (VGPR=64 -> 2-3 loads in flight). Fixes:
//  (1) __sincosf -> __sinf/__cosf (native v_sin/v_cos, ~4 ops/pair vs ~150);
//  (2) GEMM1 hoists all 16 T1 frags to regs before the MFMA chain (16 loads in
//      flight/wave); GEMM2 hoists 8 T2 frags per ps-pass. Budget: 48 state + 64
//      hoist + misc < 128 cap (1024 thr = 4 waves/SIMD hard cap).
// Structure unchanged from R9 (verified absmax 0.0117): 32 blocks x 1024 thr,
// block = 8 batch rows, full N=1024/P=128; fp8 e4m3 tables/feats/w (x64 prescale);
// per eval: pack fp8 cos/sin(phi) -> GEMM1 fp8 -> softmax -> GEMM2 fp8 -> RK4.
// 3 barriers/eval, zero cross-block traffic.
// ws: 512 KiB tables (T1 256K | T2 256K), rewritten by every block (identical bytes).

typedef __attribute__((ext_vector_type(4))) float f32x4;
typedef __attribute__((ext_vector_type(2))) float f32x2;
typedef __attribute__((ext_vector_type(8))) short bf16x8;
typedef __attribute__((ext_vector_type(4))) unsigned short u16x4;
typedef __attribute__((ext_vector_type(2))) long i64x2;

struct TCons { float s[64]; float c[64]; };

__device__ __forceinline__ unsigned short f2bf(float f) {
  unsigned u = __builtin_bit_cast(unsigned, f);
  return (unsigned short)((u + 0x7FFFu + ((u >> 16) & 1u)) >> 16);
}
// pack 8 floats -> 8 fp8 e4m3 bytes (HW cvt: byte i <-> value i, LSB first)
__device__ __forceinline__ long pk8fp8(const float* v) {
  unsigned lo = __builtin_amdgcn_cvt_pk_fp8_f32(v[0], v[1], 0, false);
  lo = __builtin_amdgcn_cvt_pk_fp8_f32(v[2], v[3], lo, true);
  unsigned hi = __builtin_amdgcn_cvt_pk_fp8_f32(v[4], v[5], 0, false);
  hi = __builtin_amdgcn_cvt_pk_fp8_f32(v[6], v[7], hi, true);
  return (long)lo | ((long)hi << 32);
}

#define A1_OFF    0        // feats fp8: 16 rows x 256 units x 8 B = 32768 (unit^row)
#define MBUF_OFF  32768    // m partials: 2 kh x 8 rows x 132 f32 = 8448
#define W_OFF     41216    // w fp8 (x64): 16 rows x 16 units x 8 B = 2048 (unit^row)
#define XST_OFF   43264    // 8 rows x 104 chunks x 16 B bf16 (encoder prologue only)
#define RED_OFF   32768    // epilogue overlay: 16 waves x 64 lanes x 16 B
#define ZP_OFF    56576    // 16 B zero page (bf16 encoder/epilogue pad rows)
#define LDS_BYTES 56592

__global__ __launch_bounds__(1024, 4) void phasenn_kernel(
    const float* __restrict__ x, const float* __restrict__ W_enc,
    const float* __restrict__ b_enc, const float* __restrict__ xi,
    const float* __restrict__ W_out, const float* __restrict__ b_out,
    float* __restrict__ dout, char* __restrict__ wsb, TCons tc)
{
  __shared__ __align__(16) char smem[LDS_BYTES];

  const int tid  = threadIdx.x;
  const int bk   = blockIdx.x;        // rows bk*8 .. bk*8+7
  const int w    = tid >> 6;          // 16 waves
  const int lane = tid & 63;
  const int q    = lane >> 4;
  const int b16  = lane & 15;         // MFMA col = batch row (0..7 used, 8..15 pad)
  const bool act = (b16 < 8);

  char* T1g = wsb;                    // 256 KiB: (pt 8, ktc 32) x 64 lanes x [cos8|sin8]
  char* T2g = wsb + (256 << 10);      // 256 KiB: (ct 64, pt2 4) x 64 lanes x [cos8|sin8]

  // ---- LDS init (before first barrier): zero pads so hot loops are branchless
  *(f32x4*)(smem + A1_OFF + 16384 + tid*16) = (f32x4){0,0,0,0};  // A1 rows 8..15
  if (tid < 256) *(unsigned*)(smem + W_OFF + 1024 + tid*4) = 0;  // W rows 8..15
  if (tid < 4)   *(unsigned*)(smem + ZP_OFF + tid*4) = 0;

  // ---- xstage: x rows -> bf16 B-frag chunks (chunk ^ row), d>=784 zero (encoder)
  {
    const int row = tid >> 7, dg = tid & 127;
    if (dg < 100) {
      bf16x8 fr = {0,0,0,0,0,0,0,0};
      if (dg < 98) {
        f32x4 v0 = *(const f32x4*)(x + (bk*8 + row)*784 + dg*8);
        f32x4 v1 = *(const f32x4*)(x + (bk*8 + row)*784 + dg*8 + 4);
        #pragma unroll
        for (int i = 0; i < 8; ++i) fr[i] = (short)f2bf(i < 4 ? v0[i] : v1[i-4]);
      }
      *(bf16x8*)(smem + XST_OFF + row*1664 + (((dg ^ row) & 127) << 4)) = fr;
    }
  }

  // ---- table gen: fp8 paired frags (identical bytes from every block; plain stores)
  if (w < 8) {  // T1: wave = ptile. lane holds p=w*16+b16, n = f*32+q*8+i; [cos|sin]
    const int p = w*16 + b16;
    for (int f = 0; f < 32; ++f) {
      const int n0 = f*32 + q*8;
      f32x4 v0 = *(const f32x4*)(xi + p*1024 + n0);
      f32x4 v1 = *(const f32x4*)(xi + p*1024 + n0 + 4);
      float cv[8], sv[8];
      #pragma unroll
      for (int i = 0; i < 8; ++i) {
        float xv = (i < 4) ? v0[i] : v1[i-4];
        sv[i] = __sinf(xv); cv[i] = __cosf(xv);
      }
      i64x2 pr; pr[0] = pk8fp8(cv); pr[1] = pk8fp8(sv);
      *(i64x2*)(T1g + (size_t)((w*32 + f)*64 + lane)*16) = pr;
    }
  } else {      // T2: lane holds n = ct*16+b16, p = pt2*32+q*8+i; [cos|sin]
    const int w2 = w - 8;
    for (int f = 0; f < 32; ++f) {
      const int ct = w2*8 + (f >> 2), pt2 = f & 3;
      const int n = ct*16 + b16;
      float cv[8], sv[8];
      #pragma unroll
      for (int i = 0; i < 8; ++i) {
        float xv = xi[(pt2*32 + q*8 + i)*1024 + n];
        sv[i] = __sinf(xv); cv[i] = __cosf(xv);
      }
      i64x2 pr; pr[0] = pk8fp8(cv); pr[1] = pk8fp8(sv);
      *(i64x2*)(T2g + (size_t)((ct*4 + pt2)*64 + lane)*16) = pr;
    }
  }
  __syncthreads();

  // ---- encoder (bf16 MFMA): D-frag -> phi regs. lane owns (row b16, n=(w*4+j)*16+q*4+r)
  float p0[16], ka[16], pwv[16];
  {
    f32x4 pac[4] = {{0,0,0,0},{0,0,0,0},{0,0,0,0},{0,0,0,0}};
    for (int kt = 0; kt < 25; ++kt) {
      const char* baddr = act
          ? (smem + XST_OFF + b16*1664 + ((((kt*4 + q) ^ b16) & 127) << 4))
          : (smem + ZP_OFF);
      bf16x8 bfr = *(const bf16x8*)baddr;
      const int d = kt*32 + q*8;
      #pragma unroll
      for (int j = 0; j < 4; ++j) {
        bf16x8 afr = {0,0,0,0,0,0,0,0};
        if (d < 784) {
          const int n = (w*4 + j)*16 + b16;
          f32x4 v0 = *(const f32x4*)(W_enc + n*784 + d);
          f32x4 v1 = *(const f32x4*)(W_enc + n*784 + d + 4);
          #pragma unroll
          for (int i = 0; i < 8; ++i) afr[i] = (short)f2bf(i < 4 ? v0[i] : v1[i-4]);
        }
        pac[j] = __builtin_amdgcn_mfma_f32_16x16x32_bf16(afr, bfr, pac[j], 0, 0, 0);
      }
    }
    #pragma unroll
    for (int j = 0; j < 4; ++j)
      #pragma unroll
      for (int r = 0; r < 4; ++r) {
        const int ix = j*4 + r;
        if (act) {
          const int n = (w*4 + j)*16 + q*4 + r;
          float ph = 6.283185307179586f / (1.0f + __expf(-(pac[j][r] + b_enc[n])));
          p0[ix] = ph; pwv[ix] = ph; ka[ix] = 0.0f;
        } else { p0[ix] = 0.0f; pwv[ix] = 0.0f; ka[ix] = 0.0f; }
      }
  }

  const float dtf = 0.03125f, half = 0.015625f;
  const float sixth = (float)(0.03125/6.0);

  for (int e = 0; e < 64; ++e) {
    // ---- Phase A: fp8 cos/sin(pw) -> A1 (8-B units, unit^row swizzle), native trig
    if (act) {
      #pragma unroll
      for (int j = 0; j < 4; ++j) {
        float c4[4], s4v[4];
        #pragma unroll
        for (int r = 0; r < 4; ++r) {
          s4v[r] = __sinf(pwv[j*4 + r]);
          c4[r]  = __cosf(pwv[j*4 + r]);
        }
        unsigned cp = __builtin_amdgcn_cvt_pk_fp8_f32(c4[0], c4[1], 0, false);
        cp = __builtin_amdgcn_cvt_pk_fp8_f32(c4[2], c4[3], cp, true);
        unsigned sp = __builtin_amdgcn_cvt_pk_fp8_f32(s4v[0], s4v[1], 0, false);
        sp = __builtin_amdgcn_cvt_pk_fp8_f32(s4v[2], s4v[3], sp, true);
        const int u = (w*4 + j)*2 + (q >> 1);
        char* base = smem + A1_OFF + b16*2048 + ((q & 1) << 2);
        *(unsigned*)(base + ((u ^ b16) << 3))          = cp;   // cos: units 0..127
        *(unsigned*)(base + 1024 + ((u ^ b16) << 3))   = sp;   // sin: units 128..255
      }
    }
    __syncthreads();

    // ---- GEMM1 fp8: hoist ALL 16 T1 frags (16 loads in flight), then MFMA chain
    {
      const int pt = w & 7, kh = w >> 3;
      const char* t1b = T1g + (size_t)((pt*32 + kh*16)*64 + lane)*16;
      const char* a1b = smem + A1_OFF + b16*2048;
      i64x2 af[16];
      #pragma unroll
      for (int i2 = 0; i2 < 16; ++i2)
        af[i2] = *(const i64x2*)(t1b + (size_t)i2*1024);
      f32x4 acc = {0.f, 0.f, 0.f, 0.f};
      #pragma unroll
      for (int i2 = 0; i2 < 16; ++i2) {
        const int ktc = kh*16 + i2;
        long bc = *(const long*)(a1b + (((ktc*4 + q) ^ b16) << 3));
        long bs = *(const long*)(a1b + 1024 + (((ktc*4 + q) ^ b16) << 3));
        acc = __builtin_amdgcn_mfma_f32_16x16x32_fp8_fp8(af[i2][0], bc, acc, 0, 0, 0);
        acc = __builtin_amdgcn_mfma_f32_16x16x32_fp8_fp8(af[i2][1], bs, acc, 0, 0, 0);
      }
      if (act)
        *(f32x4*)(smem + MBUF_OFF + kh*4224 + b16*528 + ((pt*16 + q*4) << 2)) = acc;
    }
    __syncthreads();

    // ---- softmax (waves 0..7, wave = row): w fp8 prescaled x64 (denormal-safe)
    if (w < 8) {
      const char* mb = smem + MBUF_OFF + w*528 + lane*8;
      f32x2 u0 = *(const f32x2*)(mb);
      f32x2 u1 = *(const f32x2*)(mb + 4224);
      float e0 = __expf((u0[0] + u1[0]) * 0.001953125f);  // BETA/N = 2/1024
      float e1 = __expf((u0[1] + u1[1]) * 0.001953125f);
      float s = e0 + e1;
      #pragma unroll
      for (int off = 1; off < 64; off <<= 1) s += __shfl_xor(s, off, 64);
      const float inv64 = 64.0f / s;
      unsigned pk = __builtin_amdgcn_cvt_pk_fp8_f32(e0*inv64, e1*inv64, 0, false);
      const int pp = lane*2, u = pp >> 3;
      *(unsigned short*)(smem + W_OFF + w*128 + ((u ^ w) << 3) + (pp & 7)) =
          (unsigned short)pk;
    }
    __syncthreads();

    // ---- GEMM2 fp8 + RK4: per ps-pass hoist 8 T2 frags, then MFMA; native trig
    {
      const float swt = tc.s[e], cwt = tc.c[e];
      const int st = e & 3;
      long wfr[4];
      #pragma unroll
      for (int pt2 = 0; pt2 < 4; ++pt2)
        wfr[pt2] = *(const long*)(smem + W_OFF + b16*128 + (((pt2*4 + q) ^ b16) << 3));
      #pragma unroll
      for (int ps = 0; ps < 2; ++ps) {
        i64x2 tf[8];
        #pragma unroll
        for (int jj = 0; jj < 2; ++jj) {
          const int ct = w*4 + ps*2 + jj;
          #pragma unroll
          for (int pt2 = 0; pt2 < 4; ++pt2)
            tf[jj*4 + pt2] =
                *(const i64x2*)(T2g + (size_t)((ct*4 + pt2)*64 + lane)*16);
        }
        f32x4 aC[2] = {{0,0,0,0},{0,0,0,0}}, aS[2] = {{0,0,0,0},{0,0,0,0}};
        #pragma unroll
        for (int jj = 0; jj < 2; ++jj) {
          #pragma unroll
          for (int pt2 = 0; pt2 < 4; ++pt2) {
            aC[jj] = __builtin_amdgcn_mfma_f32_16x16x32_fp8_fp8(
                tf[jj*4 + pt2][0], wfr[pt2], aC[jj], 0, 0, 0);
            aS[jj] = __builtin_amdgcn_mfma_f32_16x16x32_fp8_fp8(
                tf[jj*4 + pt2][1], wfr[pt2], aS[jj], 0, 0, 0);
          }
        }
        if (act) {
          #pragma unroll
          for (int jj = 0; jj < 2; ++jj) {
            #pragma unroll
            for (int r = 0; r < 4; ++r) {
              const int ix = (ps*2 + jj)*4 + r;
              float s_ = __sinf(pwv[ix]);
              float c_ = __cosf(pwv[ix]);
              float kv = (s_*aC[jj][r] - c_*aS[jj][r]) * 0.015625f   // /64 rescale
                       + 0.08f*(swt*c_ - cwt*s_);                    // A*sin(wt - phi)
              if (st == 0)      { ka[ix]  = kv;           pwv[ix] = p0[ix] + kv*half; }
              else if (st == 1) { ka[ix] += 2.0f*kv;      pwv[ix] = p0[ix] + kv*half; }
              else if (st == 2) { ka[ix] += 2.0f*kv;      pwv[ix] = p0[ix] + kv*dtf;  }
              else { ka[ix] += kv; p0[ix] += ka[ix]*sixth; pwv[ix] = p0[ix]; }
            }
          }
        }
      }
    }
  }

  // ---- epilogue (bf16 MFMA): out = [cos phiT, sin phiT] @ W_out^T + b_out
  __syncthreads();
  if (act) {   // pack feats bf16 into A1 region (rows b16<8, 4-KB stride)
    #pragma unroll
    for (int j = 0; j < 4; ++j) {
      u16x4 cp, sp;
      #pragma unroll
      for (int r = 0; r < 4; ++r) {
        float ph = p0[j*4 + r];
        cp[r] = f2bf(__cosf(ph)); sp[r] = f2bf(__sinf(ph));
      }
      const int cj = (w*4 + j)*2 + (q >> 1);
      char* base = smem + A1_OFF + b16*4096 + ((q & 1) << 3);
      *(u16x4*)(base + ((cj ^ b16) << 4))        = cp;
      *(u16x4*)(base + ((cj ^ b16) << 4) + 2048) = sp;
    }
  }
  __syncthreads();
  {  // D[cl][row] partial over this wave's 4 ktiles; A = W_out rows (cl<10, pad 0)
    f32x4 acc = {0.f, 0.f, 0.f, 0.f};
    #pragma unroll
    for (int i2 = 0; i2 < 4; ++i2) {
      const int kt = w*4 + i2;
      const int k = kt*32 + q*8;
      bf16x8 afr = {0,0,0,0,0,0,0,0};
      if (b16 < 10) {
        f32x4 v0 = *(const f32x4*)(W_out + b16*2048 + k);
        f32x4 v1 = *(const f32x4*)(W_out + b16*2048 + k + 4);
        #pragma unroll
        for (int i = 0; i < 8; ++i) afr[i] = (short)f2bf(i < 4 ? v0[i] : v1[i-4]);
      }
      const char* baddr = act
          ? (smem + A1_OFF + b16*4096 + ((((kt*4 + q) ^ b16) & 255) << 4))
          : (smem + ZP_OFF);
      bf16x8 bfr = *(const bf16x8*)baddr;
      acc = __builtin_amdgcn_mfma_f32_16x16x32_bf16(afr, bfr, acc, 0, 0, 0);
    }
    *(f32x4*)(smem + RED_OFF + ((w*64 + lane) << 4)) = acc;
  }
  __syncthreads();
  if (tid < 64) {   // reduce 16 wave-partials; lane: row = tid&15, cl = (tid>>4)*4+r
    f32x4 s = {0.f, 0.f, 0.f, 0.f};
    #pragma unroll
    for (int w2 = 0; w2 < 16; ++w2)
      s += *(const f32x4*)(smem + RED_OFF + ((w2*64 + tid) << 4));
    const int b = tid & 15, q2 = tid >> 4;
    if (b < 8) {
      #pragma unroll
      for (int r = 0; r < 4; ++r) {
        const int cl = q2*4 + r;
        if (cl < 10)
          dout[(bk*8 + b)*10 + cl] = s[r] + b_out[cl];
      }
    }
  }
}

extern "C" void kernel_launch(void* const* d_in, const int* in_sizes, int n_in,
                              void* d_out, int out_size, void* d_ws, size_t ws_size,
                              hipStream_t stream) {
  (void)in_sizes; (void)n_in; (void)ws_size; (void)out_size;
  const float* x     = (const float*)d_in[0];
  const float* W_enc = (const float*)d_in[1];
  const float* b_enc = (const float*)d_in[2];
  const float* xi    = (const float*)d_in[3];
  const float* W_out = (const float*)d_in[4];
  const float* b_out = (const float*)d_in[5];
  float* out = (float*)d_out;
  char* wsb = (char*)d_ws;   // 512 KiB fp8 tables; fully rewritten every launch

  TCons tc;
  const double OME = 2.0 * 3.14159265358979323846 * 200.0;
  const double dtd = 0.03125;
  const double co[4] = {0.0, 0.5, 0.5, 1.0};
  for (int e = 0; e < 64; ++e) {
    double t = ((double)(e >> 2) + co[e & 3]) * dtd;
    tc.s[e] = (float)sin(OME * t);
    tc.c[e] = (float)cos(OME * t);
  }

  phasenn_kernel<<<dim3(32), dim3(1024), 0, stream>>>(
      x, W_enc, b_enc, xi, W_out, b_out, out, wsb, tc);
}

// Round 11
// 669.833 us; speedup vs baseline: 1.3398x; 1.3398x over previous
//
#include <hip/hip_runtime.h>
#include <math.h>

// PhaseNN on MI355X.  ROUND 11: R9 structure EXACTLY + native trig only.
// R10 lesson: allocator pins VGPR=64 for 1024-thr blocks and SPILLS rather than
// grow to the 128 cap -> register-hoisting regressed (scratch traffic in WRITE).
// R11 isolates the one remaining cheap variable: __sincosf (precise libm, ~40 ops)
// -> __sinf/__cosf (native v_sin/v_cos, ~4-6 ops). Zero structural diff from the
// proven 672-us R9 kernel otherwise.
// Structure: 32 blocks x 1024 thr, block = 8 batch rows, full N=1024/P=128;
// fp8 e4m3 tables/feats/w (x64 prescale); per eval: pack fp8 cos/sin(phi) ->
// GEMM1 fp8 (interleaved loads, unroll 8) -> softmax -> GEMM2 fp8 -> RK4.
// 3 barriers/eval, zero cross-block traffic.
// ws: 512 KiB tables (T1 256K | T2 256K), rewritten by every block (identical bytes).

typedef __attribute__((ext_vector_type(4))) float f32x4;
typedef __attribute__((ext_vector_type(2))) float f32x2;
typedef __attribute__((ext_vector_type(8))) short bf16x8;
typedef __attribute__((ext_vector_type(4))) unsigned short u16x4;
typedef __attribute__((ext_vector_type(2))) long i64x2;

struct TCons { float s[64]; float c[64]; };

__device__ __forceinline__ unsigned short f2bf(float f) {
  unsigned u = __builtin_bit_cast(unsigned, f);
  return (unsigned short)((u + 0x7FFFu + ((u >> 16) & 1u)) >> 16);
}
// pack 8 floats -> 8 fp8 e4m3 bytes (HW cvt: byte i <-> value i, LSB first)
__device__ __forceinline__ long pk8fp8(const float* v) {
  unsigned lo = __builtin_amdgcn_cvt_pk_fp8_f32(v[0], v[1], 0, false);
  lo = __builtin_amdgcn_cvt_pk_fp8_f32(v[2], v[3], lo, true);
  unsigned hi = __builtin_amdgcn_cvt_pk_fp8_f32(v[4], v[5], 0, false);
  hi = __builtin_amdgcn_cvt_pk_fp8_f32(v[6], v[7], hi, true);
  return (long)lo | ((long)hi << 32);
}

#define A1_OFF    0        // feats fp8: 16 rows x 256 units x 8 B = 32768 (unit^row)
#define MBUF_OFF  32768    // m partials: 2 kh x 8 rows x 132 f32 = 8448
#define W_OFF     41216    // w fp8 (x64): 16 rows x 16 units x 8 B = 2048 (unit^row)
#define XST_OFF   43264    // 8 rows x 104 chunks x 16 B bf16 (encoder prologue only)
#define RED_OFF   32768    // epilogue overlay: 16 waves x 64 lanes x 16 B
#define ZP_OFF    56576    // 16 B zero page (bf16 encoder/epilogue pad rows)
#define LDS_BYTES 56592

__global__ __launch_bounds__(1024, 4) void phasenn_kernel(
    const float* __restrict__ x, const float* __restrict__ W_enc,
    const float* __restrict__ b_enc, const float* __restrict__ xi,
    const float* __restrict__ W_out, const float* __restrict__ b_out,
    float* __restrict__ dout, char* __restrict__ wsb, TCons tc)
{
  __shared__ __align__(16) char smem[LDS_BYTES];

  const int tid  = threadIdx.x;
  const int bk   = blockIdx.x;        // rows bk*8 .. bk*8+7
  const int w    = tid >> 6;          // 16 waves
  const int lane = tid & 63;
  const int q    = lane >> 4;
  const int b16  = lane & 15;         // MFMA col = batch row (0..7 used, 8..15 pad)
  const bool act = (b16 < 8);

  char* T1g = wsb;                    // 256 KiB: (pt 8, ktc 32) x 64 lanes x [cos8|sin8]
  char* T2g = wsb + (256 << 10);      // 256 KiB: (ct 64, pt2 4) x 64 lanes x [cos8|sin8]

  // ---- LDS init (before first barrier): zero pads so hot loops are branchless
  *(f32x4*)(smem + A1_OFF + 16384 + tid*16) = (f32x4){0,0,0,0};  // A1 rows 8..15
  if (tid < 256) *(unsigned*)(smem + W_OFF + 1024 + tid*4) = 0;  // W rows 8..15
  if (tid < 4)   *(unsigned*)(smem + ZP_OFF + tid*4) = 0;

  // ---- xstage: x rows -> bf16 B-frag chunks (chunk ^ row), d>=784 zero (encoder)
  {
    const int row = tid >> 7, dg = tid & 127;
    if (dg < 100) {
      bf16x8 fr = {0,0,0,0,0,0,0,0};
      if (dg < 98) {
        f32x4 v0 = *(const f32x4*)(x + (bk*8 + row)*784 + dg*8);
        f32x4 v1 = *(const f32x4*)(x + (bk*8 + row)*784 + dg*8 + 4);
        #pragma unroll
        for (int i = 0; i < 8; ++i) fr[i] = (short)f2bf(i < 4 ? v0[i] : v1[i-4]);
      }
      *(bf16x8*)(smem + XST_OFF + row*1664 + (((dg ^ row) & 127) << 4)) = fr;
    }
  }

  // ---- table gen: fp8 paired frags (identical bytes from every block; plain stores)
  if (w < 8) {  // T1: wave = ptile. lane holds p=w*16+b16, n = f*32+q*8+i; [cos|sin]
    const int p = w*16 + b16;
    for (int f = 0; f < 32; ++f) {
      const int n0 = f*32 + q*8;
      f32x4 v0 = *(const f32x4*)(xi + p*1024 + n0);
      f32x4 v1 = *(const f32x4*)(xi + p*1024 + n0 + 4);
      float cv[8], sv[8];
      #pragma unroll
      for (int i = 0; i < 8; ++i) {
        float xv = (i < 4) ? v0[i] : v1[i-4];
        sv[i] = __sinf(xv); cv[i] = __cosf(xv);
      }
      i64x2 pr; pr[0] = pk8fp8(cv); pr[1] = pk8fp8(sv);
      *(i64x2*)(T1g + (size_t)((w*32 + f)*64 + lane)*16) = pr;
    }
  } else {      // T2: lane holds n = ct*16+b16, p = pt2*32+q*8+i; [cos|sin]
    const int w2 = w - 8;
    for (int f = 0; f < 32; ++f) {
      const int ct = w2*8 + (f >> 2), pt2 = f & 3;
      const int n = ct*16 + b16;
      float cv[8], sv[8];
      #pragma unroll
      for (int i = 0; i < 8; ++i) {
        float xv = xi[(pt2*32 + q*8 + i)*1024 + n];
        sv[i] = __sinf(xv); cv[i] = __cosf(xv);
      }
      i64x2 pr; pr[0] = pk8fp8(cv); pr[1] = pk8fp8(sv);
      *(i64x2*)(T2g + (size_t)((ct*4 + pt2)*64 + lane)*16) = pr;
    }
  }
  __syncthreads();

  // ---- encoder (bf16 MFMA): D-frag -> phi regs. lane owns (row b16, n=(w*4+j)*16+q*4+r)
  float p0[16], ka[16], pwv[16];
  {
    f32x4 pac[4] = {{0,0,0,0},{0,0,0,0},{0,0,0,0},{0,0,0,0}};
    for (int kt = 0; kt < 25; ++kt) {
      const char* baddr = act
          ? (smem + XST_OFF + b16*1664 + ((((kt*4 + q) ^ b16) & 127) << 4))
          : (smem + ZP_OFF);
      bf16x8 bfr = *(const bf16x8*)baddr;
      const int d = kt*32 + q*8;
      #pragma unroll
      for (int j = 0; j < 4; ++j) {
        bf16x8 afr = {0,0,0,0,0,0,0,0};
        if (d < 784) {
          const int n = (w*4 + j)*16 + b16;
          f32x4 v0 = *(const f32x4*)(W_enc + n*784 + d);
          f32x4 v1 = *(const f32x4*)(W_enc + n*784 + d + 4);
          #pragma unroll
          for (int i = 0; i < 8; ++i) afr[i] = (short)f2bf(i < 4 ? v0[i] : v1[i-4]);
        }
        pac[j] = __builtin_amdgcn_mfma_f32_16x16x32_bf16(afr, bfr, pac[j], 0, 0, 0);
      }
    }
    #pragma unroll
    for (int j = 0; j < 4; ++j)
      #pragma unroll
      for (int r = 0; r < 4; ++r) {
        const int ix = j*4 + r;
        if (act) {
          const int n = (w*4 + j)*16 + q*4 + r;
          float ph = 6.283185307179586f / (1.0f + __expf(-(pac[j][r] + b_enc[n])));
          p0[ix] = ph; pwv[ix] = ph; ka[ix] = 0.0f;
        } else { p0[ix] = 0.0f; pwv[ix] = 0.0f; ka[ix] = 0.0f; }
      }
  }

  const float dtf = 0.03125f, half = 0.015625f;
  const float sixth = (float)(0.03125/6.0);

  for (int e = 0; e < 64; ++e) {
    // ---- Phase A: fp8 cos/sin(pw) -> A1 (8-B units, unit^row swizzle), native trig
    if (act) {
      #pragma unroll
      for (int j = 0; j < 4; ++j) {
        float c4[4], s4v[4];
        #pragma unroll
        for (int r = 0; r < 4; ++r) {
          s4v[r] = __sinf(pwv[j*4 + r]);
          c4[r]  = __cosf(pwv[j*4 + r]);
        }
        unsigned cp = __builtin_amdgcn_cvt_pk_fp8_f32(c4[0], c4[1], 0, false);
        cp = __builtin_amdgcn_cvt_pk_fp8_f32(c4[2], c4[3], cp, true);
        unsigned sp = __builtin_amdgcn_cvt_pk_fp8_f32(s4v[0], s4v[1], 0, false);
        sp = __builtin_amdgcn_cvt_pk_fp8_f32(s4v[2], s4v[3], sp, true);
        const int u = (w*4 + j)*2 + (q >> 1);
        char* base = smem + A1_OFF + b16*2048 + ((q & 1) << 2);
        *(unsigned*)(base + ((u ^ b16) << 3))          = cp;   // cos: units 0..127
        *(unsigned*)(base + 1024 + ((u ^ b16) << 3))   = sp;   // sin: units 128..255
      }
    }
    __syncthreads();

    // ---- GEMM1 fp8: m[p][row]; wave = (pt=w&7, kh=w>>3); interleaved stream (R9)
    {
      const int pt = w & 7, kh = w >> 3;
      f32x4 acc = {0.f, 0.f, 0.f, 0.f};
      const char* t1b = T1g + (size_t)((pt*32 + kh*16)*64 + lane)*16;
      const char* a1b = smem + A1_OFF + b16*2048;
      #pragma unroll 8
      for (int i2 = 0; i2 < 16; ++i2) {
        const int ktc = kh*16 + i2;
        i64x2 af = *(const i64x2*)(t1b + (size_t)i2*1024);
        long bc = *(const long*)(a1b + (((ktc*4 + q) ^ b16) << 3));
        long bs = *(const long*)(a1b + 1024 + (((ktc*4 + q) ^ b16) << 3));
        acc = __builtin_amdgcn_mfma_f32_16x16x32_fp8_fp8(af[0], bc, acc, 0, 0, 0);
        acc = __builtin_amdgcn_mfma_f32_16x16x32_fp8_fp8(af[1], bs, acc, 0, 0, 0);
      }
      if (act)
        *(f32x4*)(smem + MBUF_OFF + kh*4224 + b16*528 + ((pt*16 + q*4) << 2)) = acc;
    }
    __syncthreads();

    // ---- softmax (waves 0..7, wave = row): w fp8 prescaled x64 (denormal-safe)
    if (w < 8) {
      const char* mb = smem + MBUF_OFF + w*528 + lane*8;
      f32x2 u0 = *(const f32x2*)(mb);
      f32x2 u1 = *(const f32x2*)(mb + 4224);
      float e0 = __expf((u0[0] + u1[0]) * 0.001953125f);  // BETA/N = 2/1024
      float e1 = __expf((u0[1] + u1[1]) * 0.001953125f);
      float s = e0 + e1;
      #pragma unroll
      for (int off = 1; off < 64; off <<= 1) s += __shfl_xor(s, off, 64);
      const float inv64 = 64.0f / s;
      unsigned pk = __builtin_amdgcn_cvt_pk_fp8_f32(e0*inv64, e1*inv64, 0, false);
      const int pp = lane*2, u = pp >> 3;
      *(unsigned short*)(smem + W_OFF + w*128 + ((u ^ w) << 3) + (pp & 7)) =
          (unsigned short)pk;
    }
    __syncthreads();

    // ---- GEMM2 fp8 + RK4: interleaved T2 loads (R9 form), native trig in RK4
    {
      const float swt = tc.s[e], cwt = tc.c[e];
      const int st = e & 3;
      long wfr[4];
      #pragma unroll
      for (int pt2 = 0; pt2 < 4; ++pt2)
        wfr[pt2] = *(const long*)(smem + W_OFF + b16*128 + (((pt2*4 + q) ^ b16) << 3));
      #pragma unroll
      for (int ps = 0; ps < 2; ++ps) {
        f32x4 aC[2] = {{0,0,0,0},{0,0,0,0}}, aS[2] = {{0,0,0,0},{0,0,0,0}};
        #pragma unroll
        for (int jj = 0; jj < 2; ++jj) {
          const int ct = w*4 + ps*2 + jj;
          #pragma unroll
          for (int pt2 = 0; pt2 < 4; ++pt2) {
            i64x2 tf = *(const i64x2*)(T2g + (size_t)((ct*4 + pt2)*64 + lane)*16);
            aC[jj] = __builtin_amdgcn_mfma_f32_16x16x32_fp8_fp8(tf[0], wfr[pt2], aC[jj], 0,0,0);
            aS[jj] = __builtin_amdgcn_mfma_f32_16x16x32_fp8_fp8(tf[1], wfr[pt2], aS[jj], 0,0,0);
          }
        }
        if (act) {
          #pragma unroll
          for (int jj = 0; jj < 2; ++jj) {
            #pragma unroll
            for (int r = 0; r < 4; ++r) {
              const int ix = (ps*2 + jj)*4 + r;
              float s_ = __sinf(pwv[ix]);
              float c_ = __cosf(pwv[ix]);
              float kv = (s_*aC[jj][r] - c_*aS[jj][r]) * 0.015625f   // /64 rescale
                       + 0.08f*(swt*c_ - cwt*s_);                    // A*sin(wt - phi)
              if (st == 0)      { ka[ix]  = kv;           pwv[ix] = p0[ix] + kv*half; }
              else if (st == 1) { ka[ix] += 2.0f*kv;      pwv[ix] = p0[ix] + kv*half; }
              else if (st == 2) { ka[ix] += 2.0f*kv;      pwv[ix] = p0[ix] + kv*dtf;  }
              else { ka[ix] += kv; p0[ix] += ka[ix]*sixth; pwv[ix] = p0[ix]; }
            }
          }
        }
      }
    }
  }

  // ---- epilogue (bf16 MFMA): out = [cos phiT, sin phiT] @ W_out^T + b_out
  __syncthreads();
  if (act) {   // pack feats bf16 into A1 region (rows b16<8, 4-KB stride)
    #pragma unroll
    for (int j = 0; j < 4; ++j) {
      u16x4 cp, sp;
      #pragma unroll
      for (int r = 0; r < 4; ++r) {
        float ph = p0[j*4 + r];
        cp[r] = f2bf(__cosf(ph)); sp[r] = f2bf(__sinf(ph));
      }
      const int cj = (w*4 + j)*2 + (q >> 1);
      char* base = smem + A1_OFF + b16*4096 + ((q & 1) << 3);
      *(u16x4*)(base + ((cj ^ b16) << 4))        = cp;
      *(u16x4*)(base + ((cj ^ b16) << 4) + 2048) = sp;
    }
  }
  __syncthreads();
  {  // D[cl][row] partial over this wave's 4 ktiles; A = W_out rows (cl<10, pad 0)
    f32x4 acc = {0.f, 0.f, 0.f, 0.f};
    #pragma unroll
    for (int i2 = 0; i2 < 4; ++i2) {
      const int kt = w*4 + i2;
      const int k = kt*32 + q*8;
      bf16x8 afr = {0,0,0,0,0,0,0,0};
      if (b16 < 10) {
        f32x4 v0 = *(const f32x4*)(W_out + b16*2048 + k);
        f32x4 v1 = *(const f32x4*)(W_out + b16*2048 + k + 4);
        #pragma unroll
        for (int i = 0; i < 8; ++i) afr[i] = (short)f2bf(i < 4 ? v0[i] : v1[i-4]);
      }
      const char* baddr = act
          ? (smem + A1_OFF + b16*4096 + ((((kt*4 + q) ^ b16) & 255) << 4))
          : (smem + ZP_OFF);
      bf16x8 bfr = *(const bf16x8*)baddr;
      acc = __builtin_amdgcn_mfma_f32_16x16x32_bf16(afr, bfr, acc, 0, 0, 0);
    }
    *(f32x4*)(smem + RED_OFF + ((w*64 + lane) << 4)) = acc;
  }
  __syncthreads();
  if (tid < 64) {   // reduce 16 wave-partials; lane: row = tid&15, cl = (tid>>4)*4+r
    f32x4 s = {0.f, 0.f, 0.f, 0.f};
    #pragma unroll
    for (int w2 = 0; w2 < 16; ++w2)
      s += *(const f32x4*)(smem + RED_OFF + ((w2*64 + tid) << 4));
    const int b = tid & 15, q2 = tid >> 4;
    if (b < 8) {
      #pragma unroll
      for (int r = 0; r < 4; ++r) {
        const int cl = q2*4 + r;
        if (cl < 10)
          dout[(bk*8 + b)*10 + cl] = s[r] + b_out[cl];
      }
    }
  }
}

extern "C" void kernel_launch(void* const* d_in, const int* in_sizes, int n_in,
                              void* d_out, int out_size, void* d_ws, size_t ws_size,
                              hipStream_t stream) {
  (void)in_sizes; (void)n_in; (void)ws_size; (void)out_size;
  const float* x     = (const float*)d_in[0];
  const float* W_enc = (const float*)d_in[1];
  const float* b_enc = (const float*)d_in[2];
  const float* xi    = (const float*)d_in[3];
  const float* W_out = (const float*)d_in[4];
  const float* b_out = (const float*)d_in[5];
  float* out = (float*)d_out;
  char* wsb = (char*)d_ws;   // 512 KiB fp8 tables; fully rewritten every launch

  TCons tc;
  const double OME = 2.0 * 3.14159265358979323846 * 200.0;
  const double dtd = 0.03125;
  const double co[4] = {0.0, 0.5, 0.5, 1.0};
  for (int e = 0; e < 64; ++e) {
    double t = ((double)(e >> 2) + co[e & 3]) * dtd;
    tc.s[e] = (float)sin(OME * t);
    tc.c[e] = (float)cos(OME * t);
  }

  phasenn_kernel<<<dim3(32), dim3(1024), 0, stream>>>(
      x, W_enc, b_enc, xi, W_out, b_out, out, wsb, tc);
}